// Round 9
// baseline (540.772 us; speedup 1.0000x reference)
//
#include <hip/hip_runtime.h>

typedef short s8v  __attribute__((ext_vector_type(8)));
typedef float f4v  __attribute__((ext_vector_type(4)));
typedef int   v4i  __attribute__((ext_vector_type(4)));
typedef float v4f  __attribute__((ext_vector_type(4)));
typedef int   v2i  __attribute__((ext_vector_type(2)));

#define NNODES 8192
#define FDIM   256
#define NJC    4          // j-chunks
#define JLEN   2048       // columns-j per chunk
#define TROWS  32         // rows per block (R17: 32 -> 1024 blocks = 4/CU = 4 waves/SIMD)
#define KSTEP  32         // k per step = one PB k-tile
#define NSTEP  64         // JLEN / KSTEP
#define RSTR   ((size_t)16 * NNODES)   // adj rowhalf stride (16 rows)

__device__ __forceinline__ unsigned short f2bf(float f) {
    unsigned int x = __builtin_bit_cast(unsigned int, f);
    x += 0x7fffu + ((x >> 16) & 1u);
    return (unsigned short)(x >> 16);
}
// RTNE pack of 2 f32 -> 1 dword of 2 bf16
__device__ __forceinline__ int cvt_pk(float lo, float hi) {
    int r;
    asm("v_cvt_pk_bf16_f32 %0, %1, %2" : "=v"(r) : "v"(lo), "v"(hi));
    return r;
}

// p = adj>0 ? exp(leakyrelu(s1+s2)) : 0, factorized:
//   x>0  -> exp(x)    = E1*E2          (E = exp(s))
//   x<=0 -> exp(0.2x) = F1*F2          (F = exp(0.2 s))
// sign via monotonicity: E1*E2 > 1  <=>  x > 0. No transcendental per element.
__device__ __forceinline__ float pel(float e1, float f1, float e2, float f2, int ad) {
    float pp = e1 * e2;
    float pn = f1 * f2;
    float s  = (pp > 1.0f) ? pp : pn;
    return (ad > 0) ? s : 0.0f;
}

// ---------------- Kernel 0: fused WT + wv ----------------
__global__ __launch_bounds__(256) void prep_kernel(const float* __restrict__ W,
                                                   const float* __restrict__ a,
                                                   unsigned short* __restrict__ WT,
                                                   float* __restrict__ v1,
                                                   float* __restrict__ v2) {
    if (blockIdx.x < 256) {
        int idx = blockIdx.x * 256 + threadIdx.x;
        int r = idx >> 8, c = idx & 255;
        WT[c * 256 + r] = f2bf(W[r * 256 + c]);
    } else {
        __shared__ float r1[256], r2[256];
        int b = blockIdx.x - 256, n = threadIdx.x;
        float w = W[(size_t)b * FDIM + n];
        r1[n] = w * a[n];
        r2[n] = w * a[FDIM + n];
        __syncthreads();
        for (int off = 128; off > 0; off >>= 1) {
            if (n < off) { r1[n] += r1[n + off]; r2[n] += r2[n + off]; }
            __syncthreads();
        }
        if (n == 0) { v1[b] = r1[0]; v2[b] = r2[0]; }
    }
}

// ---------------- Kernel 1: PB = tiled bf16 Wh; s1/s2 = h@v (fp32) ----------------
__global__ __launch_bounds__(128) void wh_kernel(
    const float* __restrict__ h, const unsigned short* __restrict__ WT,
    const float* __restrict__ v1, const float* __restrict__ v2,
    unsigned short* __restrict__ PB,
    float* __restrict__ s1, float* __restrict__ s2)
{
    __shared__ float v1_lds[FDIM], v2_lds[FDIM];
    int tid = threadIdx.x;
    v1_lds[tid] = v1[tid];       v1_lds[tid + 128] = v1[tid + 128];
    v2_lds[tid] = v2[tid];       v2_lds[tid + 128] = v2[tid + 128];
    __syncthreads();

    int w = tid >> 6, lane = tid & 63, q = lane >> 4, l15 = lane & 15;
    int i_base = blockIdx.x * 32 + w * 16;

    f4v acc[16] = {};
    float s1p = 0.f, s2p = 0.f;

    for (int k0 = 0; k0 < 256; k0 += 32) {
        const float* hp = h + (size_t)(i_base + l15) * FDIM + k0 + q * 8;
        f4v h0 = *(const f4v*)hp;
        f4v h1 = *(const f4v*)(hp + 4);
        union { v4i u; s8v s; } af;
        af.u[0] = cvt_pk(h0[0], h0[1]);
        af.u[1] = cvt_pk(h0[2], h0[3]);
        af.u[2] = cvt_pk(h1[0], h1[1]);
        af.u[3] = cvt_pk(h1[2], h1[3]);
#pragma unroll
        for (int j = 0; j < 4; ++j) {
            s1p += h0[j] * v1_lds[k0 + q * 8 + j] + h1[j] * v1_lds[k0 + q * 8 + 4 + j];
            s2p += h0[j] * v2_lds[k0 + q * 8 + j] + h1[j] * v2_lds[k0 + q * 8 + 4 + j];
        }
#pragma unroll
        for (int t = 0; t < 16; ++t) {
            s8v bf = *(const s8v*)(WT + (size_t)(t * 16 + l15) * FDIM + k0 + q * 8);
            acc[t] = __builtin_amdgcn_mfma_f32_16x16x32_bf16(af.s, bf, acc[t], 0, 0, 0);
        }
    }

    s1p += __shfl_xor(s1p, 16, 64);
    s1p += __shfl_xor(s1p, 32, 64);
    s2p += __shfl_xor(s2p, 16, 64);
    s2p += __shfl_xor(s2p, 32, 64);
    if (lane < 16) {
        s1[i_base + lane] = s1p;
        s2[i_base + lane] = s2p;
    }

#pragma unroll
    for (int t = 0; t < 16; ++t) {
        int i0 = i_base + q * 4;
        size_t a16 = (size_t)((i0 >> 5) * 16 + t) * 512
                   + l15 * 32 + ((i0 >> 3) & 3) * 8 + (i0 & 7);
        v2i pk;
        pk[0] = cvt_pk(acc[t][0], acc[t][1]);
        pk[1] = cvt_pk(acc[t][2], acc[t][3]);
        *(v2i*)(PB + a16) = pk;
    }
}

// ---------------- Kernel 2: barrier-free attention, factorized exp ----------------
// R17 = R16 skeleton (each wave computes its own A-frags in registers; no
// P_lds, no in-loop barriers) with the two measured costs removed:
//   (1) VALU/element: 8+ ops incl quarter-rate exp -> 7 cheap ops via the
//       E/F factorization (exps hoisted: 4/lane + 16/thread one-time).
//   (2) 2 waves/SIMD -> 4: TROWS 32, grid 1024 = 4 blocks/CU, cap 128 VGPR.
// adj depth-2-ish reload prefetch (consume s, reload s+2); bf double-buffer
// 1 step ahead (L2-hit). jc=bid&3 pins one 1-MiB PB slice per XCD.
__global__ __launch_bounds__(256, 4) void attn_partial(
    const int* __restrict__ adj, const unsigned short* __restrict__ PB,
    const float* __restrict__ s1, const float* __restrict__ s2,
    float* __restrict__ Npart, float* __restrict__ dpart)
{
    __shared__ float s2ef[JLEN * 2];   // 16 KB: {E2,F2} per column

    int tid = threadIdx.x;
    int jc = blockIdx.x & 3, rt = blockIdx.x >> 2;
    int j0 = jc * JLEN;

    // stage E2/F2 (one-time 16 exps/thread)
    for (int i = tid; i < JLEN; i += 256) {
        float x = s2[j0 + i];
        s2ef[2 * i]     = __expf(x);
        s2ef[2 * i + 1] = __expf(0.2f * x);
    }

    int g = tid >> 6, lane = tid & 63, q = lane >> 4, l15 = lane & 15;

    // per-row E1/F1 for this lane's 2 rows (rh*16 + l15)
    float E1[2], F1[2];
#pragma unroll
    for (int rh = 0; rh < 2; ++rh) {
        float s1v = s1[rt * TROWS + rh * 16 + l15];
        E1[rh] = __expf(s1v);
        F1[rh] = __expf(0.2f * s1v);
    }

    const unsigned short* pbb = PB + (size_t)(jc * NSTEP) * 16 * 512 + l15 * 32 + q * 8;
    const int* arow = adj + (size_t)(rt * TROWS + l15) * NNODES + j0 + q * 8;

    f4v acc[2][4] = {};
    float ds[2] = {0.f, 0.f};

    __syncthreads();  // s2ef staged -- the only barrier

    // prologue: adj for step0 (aC) and step1 (aN); bf frags for step 0
    v4i aC[2][2], aN[2][2];
#pragma unroll
    for (int rh = 0; rh < 2; ++rh) {
        const int* pp = arow + rh * RSTR;
        aC[rh][0] = *(const v4i*)(pp);
        aC[rh][1] = *(const v4i*)(pp + 4);
        aN[rh][0] = *(const v4i*)(pp + KSTEP);
        aN[rh][1] = *(const v4i*)(pp + KSTEP + 4);
    }
    s8v bfA[4], bfB[4];
#pragma unroll
    for (int t = 0; t < 4; ++t)
        bfA[t] = *(const s8v*)(pbb + (size_t)(g * 4 + t) * 512);

// Step S: consume AC (adj for S) + BC (bf for S); issue bf(S+1) into BN and
// adj(S+2) back into AC (ready 2 steps later). No barriers.
#define ASTEP(S, AC, BC, BN) do {                                             \
    int sc = (S);                                                             \
    int sb = (sc + 1 < NSTEP) ? sc + 1 : 0;                                   \
    _Pragma("unroll")                                                         \
    for (int t = 0; t < 4; ++t)                                               \
        BN[t] = *(const s8v*)(pbb + (size_t)(sb * 16 + g * 4 + t) * 512);     \
    int sn = (sc + 2 < NSTEP) ? sc + 2 : 0;                                   \
    const float* efp = &s2ef[(sc * KSTEP + q * 8) * 2];                       \
    v4f e01 = *(const v4f*)(efp);                                             \
    v4f e23 = *(const v4f*)(efp + 4);                                         \
    v4f e45 = *(const v4f*)(efp + 8);                                         \
    v4f e67 = *(const v4f*)(efp + 12);                                        \
    _Pragma("unroll")                                                         \
    for (int rh = 0; rh < 2; ++rh) {                                          \
        float p0 = pel(E1[rh], F1[rh], e01[0], e01[1], AC[rh][0][0]);         \
        float p1 = pel(E1[rh], F1[rh], e01[2], e01[3], AC[rh][0][1]);         \
        float p2 = pel(E1[rh], F1[rh], e23[0], e23[1], AC[rh][0][2]);         \
        float p3 = pel(E1[rh], F1[rh], e23[2], e23[3], AC[rh][0][3]);         \
        float p4 = pel(E1[rh], F1[rh], e45[0], e45[1], AC[rh][1][0]);         \
        float p5 = pel(E1[rh], F1[rh], e45[2], e45[3], AC[rh][1][1]);         \
        float p6 = pel(E1[rh], F1[rh], e67[0], e67[1], AC[rh][1][2]);         \
        float p7 = pel(E1[rh], F1[rh], e67[2], e67[3], AC[rh][1][3]);         \
        ds[rh] += ((p0 + p1) + (p2 + p3)) + ((p4 + p5) + (p6 + p7));          \
        union { v4i u; s8v s; } af;                                           \
        af.u[0] = cvt_pk(p0, p1);  af.u[1] = cvt_pk(p2, p3);                  \
        af.u[2] = cvt_pk(p4, p5);  af.u[3] = cvt_pk(p6, p7);                  \
        _Pragma("unroll")                                                     \
        for (int t = 0; t < 4; ++t)                                           \
            acc[rh][t] = __builtin_amdgcn_mfma_f32_16x16x32_bf16(af.s, BC[t], acc[rh][t], 0, 0, 0); \
        const int* pp2 = arow + rh * RSTR + (size_t)sn * KSTEP;               \
        AC[rh][0] = *(const v4i*)(pp2);                                       \
        AC[rh][1] = *(const v4i*)(pp2 + 4);                                   \
    }                                                                         \
} while (0)

    for (int s = 0; s < NSTEP; s += 2) {
        ASTEP(s,     aC, bfA, bfB);
        ASTEP(s + 1, aN, bfB, bfA);
    }
#undef ASTEP

    // denominator: lanes hold q-slice partials; reduce over q (lane bits 4,5);
    // all 4 waves identical -> wave 0 writes.
#pragma unroll
    for (int rh = 0; rh < 2; ++rh) {
        ds[rh] += __shfl_xor(ds[rh], 16, 64);
        ds[rh] += __shfl_xor(ds[rh], 32, 64);
    }
    if (g == 0 && lane < 16) {
#pragma unroll
        for (int rh = 0; rh < 2; ++rh)
            dpart[jc * NNODES + rt * TROWS + rh * 16 + lane] = ds[rh];
    }

    // partial numerator: row = rh*16 + q*4 + r, col = g*64 + t*16 + l15
#pragma unroll
    for (int rh = 0; rh < 2; ++rh)
#pragma unroll
        for (int r = 0; r < 4; ++r) {
            int row = rh * 16 + q * 4 + r;
            float* base = Npart + ((size_t)(jc * NNODES) + rt * TROWS + row) * FDIM;
#pragma unroll
            for (int t = 0; t < 4; ++t)
                __builtin_nontemporal_store(acc[rh][t][r], base + g * 64 + t * 16 + l15);
        }
}

// ---------------- Kernel 3: reduce partials, normalize ----------------
__global__ __launch_bounds__(256) void reduce_kernel(
    const float* __restrict__ Npart, const float* __restrict__ dpart,
    float* __restrict__ out)
{
    int i = blockIdx.x, n = threadIdx.x;
    float d = 0.f, acc = 0.f;
#pragma unroll
    for (int jc = 0; jc < NJC; ++jc) {
        d += dpart[jc * NNODES + i];
        acc += Npart[((size_t)(jc * NNODES) + i) * FDIM + n];
    }
    out[(size_t)i * FDIM + n] = acc / fmaxf(d, 1e-30f);
}

extern "C" void kernel_launch(void* const* d_in, const int* in_sizes, int n_in,
                              void* d_out, int out_size, void* d_ws, size_t ws_size,
                              hipStream_t stream) {
    const float* h   = (const float*)d_in[0];
    const int*   adj = (const int*)d_in[1];
    const float* W   = (const float*)d_in[2];
    const float* a   = (const float*)d_in[3];
    float* out = (float*)d_out;

    char* ws = (char*)d_ws;
    unsigned short* PB = (unsigned short*)ws;                  // 4 MiB (tiled Wh)
    float* s1 = (float*)(ws + (4u << 20));                     // 32 KiB
    float* s2 = (float*)(ws + (4u << 20) + (32u << 10));       // 32 KiB
    unsigned short* WT = (unsigned short*)(ws + (4u << 20) + (64u << 10));   // 128 KiB
    float* v1 = (float*)(ws + (4u << 20) + (192u << 10));      // 1 KiB
    float* v2 = (float*)(ws + (4u << 20) + (193u << 10));      // 1 KiB
    float* dpart = (float*)(ws + (5u << 20));                  // 128 KiB
    float* Npart = (float*)(ws + (8u << 20));                  // 32 MiB

    hipLaunchKernelGGL(prep_kernel, dim3(512), dim3(256), 0, stream, W, a, WT, v1, v2);
    hipLaunchKernelGGL(wh_kernel, dim3(256), dim3(128), 0, stream, h, WT, v1, v2, PB, s1, s2);
    hipLaunchKernelGGL(attn_partial, dim3((NNODES / TROWS) * NJC), dim3(256), 0, stream,
                       adj, PB, s1, s2, Npart, dpart);
    hipLaunchKernelGGL(reduce_kernel, dim3(NNODES), dim3(256), 0, stream, Npart, dpart, out);
}

// Round 10
// 447.478 us; speedup vs baseline: 1.2085x; 1.2085x over previous
//
#include <hip/hip_runtime.h>

typedef short s8v  __attribute__((ext_vector_type(8)));
typedef float f4v  __attribute__((ext_vector_type(4)));
typedef int   v4i  __attribute__((ext_vector_type(4)));
typedef float v4f  __attribute__((ext_vector_type(4)));
typedef int   v2i  __attribute__((ext_vector_type(2)));

#define NNODES 8192
#define FDIM   256
#define NJC    4          // j-chunks (R2-best geometry, unchanged)
#define JLEN   2048       // columns-j per chunk
#define TROWS  64         // rows per block
#define KSTEP  32         // k per step = one PB k-tile
#define NSTEP  64         // JLEN / KSTEP

__device__ __forceinline__ unsigned short f2bf(float f) {
    unsigned int x = __builtin_bit_cast(unsigned int, f);
    x += 0x7fffu + ((x >> 16) & 1u);
    return (unsigned short)(x >> 16);
}
// RTNE pack of 2 f32 -> 1 dword of 2 bf16
__device__ __forceinline__ int cvt_pk(float lo, float hi) {
    int r;
    asm("v_cvt_pk_bf16_f32 %0, %1, %2" : "=v"(r) : "v"(lo), "v"(hi));
    return r;
}

// p = adj>0 ? exp(leakyrelu(s1+s2,0.2)) : 0, factorized (R9-proven numerics):
//   x>0 -> exp(x) = E1*E2 ; x<=0 -> exp(0.2x) = F1*F2 ; sign: E1*E2>1 <=> x>0.
__device__ __forceinline__ float pel(float E1, float F1, float e2, float f2, int ad) {
    float pp = E1 * e2;
    float pn = F1 * f2;
    float s  = (pp > 1.0f) ? pp : pn;
    return (ad > 0) ? s : 0.0f;
}

// Barrier WITHOUT vmcnt drain (R2): LDS visibility needs only lgkmcnt(0).
__device__ __forceinline__ void barrier_lds_only() {
    asm volatile("s_waitcnt lgkmcnt(0)" ::: "memory");
    __builtin_amdgcn_s_barrier();
    asm volatile("" ::: "memory");
}

// ---------------- Kernel 0: fused WT + wv ----------------
__global__ __launch_bounds__(256) void prep_kernel(const float* __restrict__ W,
                                                   const float* __restrict__ a,
                                                   unsigned short* __restrict__ WT,
                                                   float* __restrict__ v1,
                                                   float* __restrict__ v2) {
    if (blockIdx.x < 256) {
        int idx = blockIdx.x * 256 + threadIdx.x;
        int r = idx >> 8, c = idx & 255;
        WT[c * 256 + r] = f2bf(W[r * 256 + c]);
    } else {
        __shared__ float r1[256], r2[256];
        int b = blockIdx.x - 256, n = threadIdx.x;
        float w = W[(size_t)b * FDIM + n];
        r1[n] = w * a[n];
        r2[n] = w * a[FDIM + n];
        __syncthreads();
        for (int off = 128; off > 0; off >>= 1) {
            if (n < off) { r1[n] += r1[n + off]; r2[n] += r2[n + off]; }
            __syncthreads();
        }
        if (n == 0) { v1[b] = r1[0]; v2[b] = r2[0]; }
    }
}

// ---------------- Kernel 1: PB = tiled bf16 Wh; s1/s2 = h@v (fp32) ----------------
__global__ __launch_bounds__(128) void wh_kernel(
    const float* __restrict__ h, const unsigned short* __restrict__ WT,
    const float* __restrict__ v1, const float* __restrict__ v2,
    unsigned short* __restrict__ PB,
    float* __restrict__ s1, float* __restrict__ s2)
{
    __shared__ float v1_lds[FDIM], v2_lds[FDIM];
    int tid = threadIdx.x;
    v1_lds[tid] = v1[tid];       v1_lds[tid + 128] = v1[tid + 128];
    v2_lds[tid] = v2[tid];       v2_lds[tid + 128] = v2[tid + 128];
    __syncthreads();

    int w = tid >> 6, lane = tid & 63, q = lane >> 4, l15 = lane & 15;
    int i_base = blockIdx.x * 32 + w * 16;

    f4v acc[16] = {};
    float s1p = 0.f, s2p = 0.f;

    for (int k0 = 0; k0 < 256; k0 += 32) {
        const float* hp = h + (size_t)(i_base + l15) * FDIM + k0 + q * 8;
        f4v h0 = *(const f4v*)hp;
        f4v h1 = *(const f4v*)(hp + 4);
        union { v4i u; s8v s; } af;
        af.u[0] = cvt_pk(h0[0], h0[1]);
        af.u[1] = cvt_pk(h0[2], h0[3]);
        af.u[2] = cvt_pk(h1[0], h1[1]);
        af.u[3] = cvt_pk(h1[2], h1[3]);
#pragma unroll
        for (int j = 0; j < 4; ++j) {
            s1p += h0[j] * v1_lds[k0 + q * 8 + j] + h1[j] * v1_lds[k0 + q * 8 + 4 + j];
            s2p += h0[j] * v2_lds[k0 + q * 8 + j] + h1[j] * v2_lds[k0 + q * 8 + 4 + j];
        }
#pragma unroll
        for (int t = 0; t < 16; ++t) {
            s8v bf = *(const s8v*)(WT + (size_t)(t * 16 + l15) * FDIM + k0 + q * 8);
            acc[t] = __builtin_amdgcn_mfma_f32_16x16x32_bf16(af.s, bf, acc[t], 0, 0, 0);
        }
    }

    s1p += __shfl_xor(s1p, 16, 64);
    s1p += __shfl_xor(s1p, 32, 64);
    s2p += __shfl_xor(s2p, 16, 64);
    s2p += __shfl_xor(s2p, 32, 64);
    if (lane < 16) {
        s1[i_base + lane] = s1p;
        s2[i_base + lane] = s2p;
    }

#pragma unroll
    for (int t = 0; t < 16; ++t) {
        int i0 = i_base + q * 4;
        size_t a16 = (size_t)((i0 >> 5) * 16 + t) * 512
                   + l15 * 32 + ((i0 >> 3) & 3) * 8 + (i0 & 7);
        v2i pk;
        pk[0] = cvt_pk(acc[t][0], acc[t][1]);
        pk[1] = cvt_pk(acc[t][2], acc[t][3]);
        *(v2i*)(PB + a16) = pk;
    }
}

// ---------------- Kernel 2: split-K partial attention (R2 base + E/F math) ----------------
// Identical to the 439-us R2 kernel except the P-gen arithmetic: __expf in
// the loop replaced by hoisted E/F products (E2/F2 staged once in LDS,
// E1/F1 per-row). One variable isolated on the best-known base.
__global__ __launch_bounds__(256, 3) void attn_partial(
    const int* __restrict__ adj, const unsigned short* __restrict__ PB,
    const float* __restrict__ s1, const float* __restrict__ s2,
    float* __restrict__ Npart, float* __restrict__ dpart)
{
    __shared__ float s2ef[JLEN * 2];                    // 16 KB: {E2,F2} per col
    __shared__ unsigned short P_lds[2][TROWS * KSTEP];  // 2 x 4 KB
    __shared__ float dsum_lds[TROWS][4];

    int tid = threadIdx.x;
    int rt = blockIdx.x & 127, jc = blockIdx.x >> 7;
    int j0 = jc * JLEN;

    // stage E2/F2 (one-time 16 exps/thread)
    for (int i = tid; i < JLEN; i += 256) {
        float x = s2[j0 + i];
        s2ef[2 * i]     = __expf(x);
        s2ef[2 * i + 1] = __expf(0.2f * x);
    }

    // P-generator role: (row m 0..63, k-slice idx 0..3), 8 j's per thread/step
    int m = tid >> 2, idx = tid & 3;
    int row_g = rt * TROWS + m;
    float s1v = s1[row_g];
    float E1v = __expf(s1v), F1v = __expf(0.2f * s1v);
    const int* arow = adj + (size_t)row_g * NNODES + j0 + idx * 8;
    int woff = ((idx * 64 + m) * 8) ^ (idx * 16);

    // MFMA role: wave g -> cols g*64 + t*16 + l15; rowhalves rh=0..3 in-register
    int g = tid >> 6, lane = tid & 63, q = lane >> 4, l15 = lane & 15;
    const unsigned short* pbb = PB + (size_t)(jc * 64) * 16 * 512 + l15 * 32 + q * 8;

    f4v acc[4][4] = {};
    float dsum = 0.0f;

    __syncthreads();  // s2ef staged

    // prologue: adj(step0) -> P0; adj(step1) parked in cur
    v4i a0 = __builtin_nontemporal_load((const v4i*)(arow));
    v4i a1 = __builtin_nontemporal_load((const v4i*)(arow + 4));
    v4i cur0 = __builtin_nontemporal_load((const v4i*)(arow + KSTEP));
    v4i cur1 = __builtin_nontemporal_load((const v4i*)(arow + KSTEP + 4));
    {
        const float* efp = &s2ef[(idx * 8) * 2];
        v4f e0 = *(const v4f*)(efp);
        v4f e1 = *(const v4f*)(efp + 4);
        v4f e2 = *(const v4f*)(efp + 8);
        v4f e3 = *(const v4f*)(efp + 12);
        float p0 = pel(E1v, F1v, e0[0], e0[1], a0[0]);
        float p1 = pel(E1v, F1v, e0[2], e0[3], a0[1]);
        float p2 = pel(E1v, F1v, e1[0], e1[1], a0[2]);
        float p3 = pel(E1v, F1v, e1[2], e1[3], a0[3]);
        float p4 = pel(E1v, F1v, e2[0], e2[1], a1[0]);
        float p5 = pel(E1v, F1v, e2[2], e2[3], a1[1]);
        float p6 = pel(E1v, F1v, e3[0], e3[1], a1[2]);
        float p7 = pel(E1v, F1v, e3[2], e3[3], a1[3]);
        dsum += ((p0 + p1) + (p2 + p3)) + ((p4 + p5) + (p6 + p7));
        v4i pv;
        pv[0] = cvt_pk(p0, p1);
        pv[1] = cvt_pk(p2, p3);
        pv[2] = cvt_pk(p4, p5);
        pv[3] = cvt_pk(p6, p7);
        *(v4i*)&P_lds[0][woff] = pv;
    }
    barrier_lds_only();

    for (int s = 0; s < NSTEP; ++s) {
        // adj for step s+2 (stays in flight across the lgkm-only barrier)
        int kn = (s < NSTEP - 2) ? (s + 2) * KSTEP : 0;
        v4i nx0 = __builtin_nontemporal_load((const v4i*)(arow + kn));
        v4i nx1 = __builtin_nontemporal_load((const v4i*)(arow + kn + 4));

        // B-frags for step s: contiguous 1 KiB per wave, reused over 4 rowhalves
        s8v bf[4];
#pragma unroll
        for (int t = 0; t < 4; ++t)
            bf[t] = *(const s8v*)(pbb + (size_t)(s * 16 + g * 4 + t) * 512);

        // P for step s+1 from cur (E/F products, no transcendental)
        if (s < NSTEP - 1) {
            const float* efp = &s2ef[((s + 1) * KSTEP + idx * 8) * 2];
            v4f e0 = *(const v4f*)(efp);
            v4f e1 = *(const v4f*)(efp + 4);
            v4f e2 = *(const v4f*)(efp + 8);
            v4f e3 = *(const v4f*)(efp + 12);
            float p0 = pel(E1v, F1v, e0[0], e0[1], cur0[0]);
            float p1 = pel(E1v, F1v, e0[2], e0[3], cur0[1]);
            float p2 = pel(E1v, F1v, e1[0], e1[1], cur0[2]);
            float p3 = pel(E1v, F1v, e1[2], e1[3], cur0[3]);
            float p4 = pel(E1v, F1v, e2[0], e2[1], cur1[0]);
            float p5 = pel(E1v, F1v, e2[2], e2[3], cur1[1]);
            float p6 = pel(E1v, F1v, e3[0], e3[1], cur1[2]);
            float p7 = pel(E1v, F1v, e3[2], e3[3], cur1[3]);
            dsum += ((p0 + p1) + (p2 + p3)) + ((p4 + p5) + (p6 + p7));
            v4i pv;
            pv[0] = cvt_pk(p0, p1);
            pv[1] = cvt_pk(p2, p3);
            pv[2] = cvt_pk(p4, p5);
            pv[3] = cvt_pk(p6, p7);
            *(v4i*)&P_lds[(s + 1) & 1][woff] = pv;
        }

        // MFMA over 4 rowhalves
        const unsigned short* pbuf = P_lds[s & 1];
#pragma unroll
        for (int rh = 0; rh < 4; ++rh) {
            s8v af = *(const s8v*)&pbuf[((q * 64 + rh * 16 + l15) * 8) ^ (q * 16)];
#pragma unroll
            for (int t = 0; t < 4; ++t)
                acc[rh][t] = __builtin_amdgcn_mfma_f32_16x16x32_bf16(af, bf[t], acc[rh][t], 0, 0, 0);
        }

        barrier_lds_only();
        cur0 = nx0; cur1 = nx1;
    }

    // partial denominator
    dsum_lds[m][idx] = dsum;
    __syncthreads();
    if (tid < TROWS) {
        float d = dsum_lds[tid][0] + dsum_lds[tid][1] + dsum_lds[tid][2] + dsum_lds[tid][3];
        dpart[jc * NNODES + rt * TROWS + tid] = d;
    }

    // partial numerator: row = rh*16 + q*4 + r, col = g*64 + t*16 + l15
#pragma unroll
    for (int rh = 0; rh < 4; ++rh)
#pragma unroll
        for (int r = 0; r < 4; ++r) {
            int row = rh * 16 + q * 4 + r;
            float* base = Npart + ((size_t)(jc * NNODES) + rt * TROWS + row) * FDIM;
#pragma unroll
            for (int t = 0; t < 4; ++t)
                __builtin_nontemporal_store(acc[rh][t][r], base + g * 64 + t * 16 + l15);
        }
}

// ---------------- Kernel 3: reduce partials, normalize ----------------
__global__ __launch_bounds__(256) void reduce_kernel(
    const float* __restrict__ Npart, const float* __restrict__ dpart,
    float* __restrict__ out)
{
    int i = blockIdx.x, n = threadIdx.x;
    float d = 0.f, acc = 0.f;
#pragma unroll
    for (int jc = 0; jc < NJC; ++jc) {
        d += dpart[jc * NNODES + i];
        acc += Npart[((size_t)(jc * NNODES) + i) * FDIM + n];
    }
    out[(size_t)i * FDIM + n] = acc / fmaxf(d, 1e-30f);
}

extern "C" void kernel_launch(void* const* d_in, const int* in_sizes, int n_in,
                              void* d_out, int out_size, void* d_ws, size_t ws_size,
                              hipStream_t stream) {
    const float* h   = (const float*)d_in[0];
    const int*   adj = (const int*)d_in[1];
    const float* W   = (const float*)d_in[2];
    const float* a   = (const float*)d_in[3];
    float* out = (float*)d_out;

    char* ws = (char*)d_ws;
    unsigned short* PB = (unsigned short*)ws;                  // 4 MiB (tiled Wh)
    float* s1 = (float*)(ws + (4u << 20));                     // 32 KiB
    float* s2 = (float*)(ws + (4u << 20) + (32u << 10));       // 32 KiB
    unsigned short* WT = (unsigned short*)(ws + (4u << 20) + (64u << 10));   // 128 KiB
    float* v1 = (float*)(ws + (4u << 20) + (192u << 10));      // 1 KiB
    float* v2 = (float*)(ws + (4u << 20) + (193u << 10));      // 1 KiB
    float* dpart = (float*)(ws + (5u << 20));                  // 128 KiB
    float* Npart = (float*)(ws + (8u << 20));                  // 32 MiB

    hipLaunchKernelGGL(prep_kernel, dim3(512), dim3(256), 0, stream, W, a, WT, v1, v2);
    hipLaunchKernelGGL(wh_kernel, dim3(256), dim3(128), 0, stream, h, WT, v1, v2, PB, s1, s2);
    hipLaunchKernelGGL(attn_partial, dim3(128 * NJC), dim3(256), 0, stream,
                       adj, PB, s1, s2, Npart, dpart);
    hipLaunchKernelGGL(reduce_kernel, dim3(NNODES), dim3(256), 0, stream, Npart, dpart, out);
}